// Round 10
// baseline (160.329 us; speedup 1.0000x reference)
//
#include <hip/hip_runtime.h>
#include <stdint.h>

#define N 4096
#define B 2
#define D 128
#define LOG2E 1.4426950408889634f

typedef float f32x4 __attribute__((ext_vector_type(4)));

__device__ __forceinline__ float lrelu(float t) { return t > 0.f ? t : 0.01f * t; }

// Node 1: fused u-vector + row dots. 512 blocks x 256 threads; block owns 16 rows.
// Phase A (validated in r7 kfused): every block redundantly computes
// u_l[d]=sum_e Wa[e,d]*w_l[e], u_r likewise (Wa is 64KB, L2-hot).
// Phase B: wave w computes rows blk*16+w*4..+3: demands->out, l->lv, r->colR.
__global__ __launch_bounds__(256) void kA_rows(
    const float* __restrict__ x,      // [B*N, D]
    const float* __restrict__ Wd,     // [D]
    const float* __restrict__ bd,     // [1]
    const float* __restrict__ Wa,     // [D, D]
    const float* __restrict__ w_l,    // [D]
    const float* __restrict__ w_r,    // [D]
    float* __restrict__ out_dem,      // [B*N] (start of d_out)
    float* __restrict__ lv,           // [B*N]  l in exp2 domain
    float* __restrict__ colR) {       // [B*N]  r in exp2 domain
    __shared__ float uLR[2][D];
    __shared__ float sWd[D];
    int t = threadIdx.x;
    int lane = t & 63;
    int w = t >> 6;
    int row0 = blockIdx.x << 4;

    // Phase A
    {
        int d = t & 127;
        int sel = t >> 7;                      // wave-uniform: 0->l, 1->r
        const float* wv = sel ? w_r : w_l;
        float acc = 0.f;
        #pragma unroll 8
        for (int e = 0; e < 128; ++e)
            acc += Wa[e * 128 + d] * wv[e];    // coalesced, L2-hot
        uLR[sel][d] = acc;
        if (t < 128) sWd[t] = Wd[t];
    }
    __syncthreads();

    // Phase B
    float2 ul2 = ((const float2*)uLR[0])[lane];
    float2 ur2 = ((const float2*)uLR[1])[lane];
    float2 wd2 = ((const float2*)sWd)[lane];
    #pragma unroll
    for (int rr = 0; rr < 4; ++rr) {
        int row = row0 + w * 4 + rr;
        float2 xv = ((const float2*)(x + (size_t)row * D))[lane];
        float pl = xv.x * ul2.x + xv.y * ul2.y;
        float pr = xv.x * ur2.x + xv.y * ur2.y;
        float pd = xv.x * wd2.x + xv.y * wd2.y;
        #pragma unroll
        for (int m = 32; m >= 1; m >>= 1) {
            pl += __shfl_xor(pl, m, 64);
            pr += __shfl_xor(pr, m, 64);
            pd += __shfl_xor(pd, m, 64);
        }
        if (lane == 0) {
            out_dem[row] = 1.f / (1.f + __expf(-(pd + bd[0])));
            lv[row] = pl * LOG2E;            // exp2 domain (lrelu commutes w/ pos scale)
            colR[row] = pr * LOG2E;
        }
    }
}

// Node 2: rmax + factor tables (LDS) + denominators + CONTIGUOUS writer.
// 1024 blocks x 256 threads; block owns 8 adjacent rows (128KB contiguous output);
// wave w owns rows i0+2w, i0+2w+1 (32KB contiguous per wave).
// Write loop operands come from LDS only (lgkmcnt; never drains store vmcnt).
// Factorization: out = (Fp_j > thr_i) ? eP_i*Fp_j : eM_i*Fm_j, with
//   Fp=exp2(r-rmax), Fm=exp2(0.01(r-rmax)), thr=exp2(-(l+rmax)),
//   eP=exp2(l+rmax-m0)*sc, eM=exp2(0.01(l+rmax)-m0)*sc, m0=lrelu(l+rmax),
//   sc=dem/(Ep*S1+Em*S2), S1=sum_{pos}Fp, S2=sum_{neg}Fm.
__global__ __launch_bounds__(256) void kB_write(
    const float* __restrict__ lv,
    const float* __restrict__ colR,
    const float* __restrict__ dem_f,      // demands (start of d_out)
    float* __restrict__ out_g) {          // [B,N,N] fp32 (16B-aligned)
    __shared__ float sFp[N];              // 16KB
    __shared__ float sFm[N];              // 16KB
    __shared__ float redm[4];
    int t = threadIdx.x;
    int lane = t & 63;
    int w = t >> 6;
    int i0 = blockIdx.x << 3;             // global row base (incl. batch)
    int b = i0 >> 12;

    // rmax (block-redundant, over the full batch) + tables into LDS
    const float4* rB = (const float4*)(colR + ((size_t)b << 12));
    float4 loc[4];
    float m = -3.402823466e38f;
    #pragma unroll
    for (int k = 0; k < 4; ++k) {
        loc[k] = rB[t + k * 256];          // coalesced, L2-hot (16KB/batch)
        m = fmaxf(fmaxf(m, fmaxf(loc[k].x, loc[k].y)), fmaxf(loc[k].z, loc[k].w));
    }
    #pragma unroll
    for (int s = 32; s >= 1; s >>= 1) m = fmaxf(m, __shfl_xor(m, s, 64));
    if (lane == 0) redm[w] = m;
    __syncthreads();
    float rmax = fmaxf(fmaxf(redm[0], redm[1]), fmaxf(redm[2], redm[3]));
    #pragma unroll
    for (int k = 0; k < 4; ++k) {
        int idx = t + k * 256;             // float4 index
        float4 v = loc[k];
        ((float4*)sFp)[idx] = make_float4(exp2f(v.x - rmax), exp2f(v.y - rmax),
                                          exp2f(v.z - rmax), exp2f(v.w - rmax));
        ((float4*)sFm)[idx] = make_float4(exp2f(0.01f * (v.x - rmax)),
                                          exp2f(0.01f * (v.y - rmax)),
                                          exp2f(0.01f * (v.z - rmax)),
                                          exp2f(0.01f * (v.w - rmax)));
    }
    __syncthreads();

    // per-wave: denominators for rows rowA, rowA+1
    int rowA = i0 + 2 * w;
    float lA = lv[rowA], lB = lv[rowA + 1];
    float tA = lA + rmax, tB = lB + rmax;
    float thrA = exp2f(-tA), thrB = exp2f(-tB);
    float s1a = 0.f, s2a = 0.f, s1b = 0.f, s2b = 0.f;
    #pragma unroll 4
    for (int seg = 0; seg < 16; ++seg) {
        int idx = seg * 64 + lane;
        float4 fp = ((const float4*)sFp)[idx];
        float4 fm = ((const float4*)sFm)[idx];
        s1a += (fp.x > thrA ? fp.x : 0.f) + (fp.y > thrA ? fp.y : 0.f)
             + (fp.z > thrA ? fp.z : 0.f) + (fp.w > thrA ? fp.w : 0.f);
        s2a += (fp.x > thrA ? 0.f : fm.x) + (fp.y > thrA ? 0.f : fm.y)
             + (fp.z > thrA ? 0.f : fm.z) + (fp.w > thrA ? 0.f : fm.w);
        s1b += (fp.x > thrB ? fp.x : 0.f) + (fp.y > thrB ? fp.y : 0.f)
             + (fp.z > thrB ? fp.z : 0.f) + (fp.w > thrB ? fp.w : 0.f);
        s2b += (fp.x > thrB ? 0.f : fm.x) + (fp.y > thrB ? 0.f : fm.y)
             + (fp.z > thrB ? 0.f : fm.z) + (fp.w > thrB ? 0.f : fm.w);
    }
    #pragma unroll
    for (int s = 32; s >= 1; s >>= 1) {
        s1a += __shfl_xor(s1a, s, 64);
        s2a += __shfl_xor(s2a, s, 64);
        s1b += __shfl_xor(s1b, s, 64);
        s2b += __shfl_xor(s2b, s, 64);
    }
    float m0A = lrelu(tA), m0B = lrelu(tB);
    float EpA = exp2f(tA - m0A), EmA = exp2f(0.01f * tA - m0A);
    float EpB = exp2f(tB - m0B), EmB = exp2f(0.01f * tB - m0B);
    float scA = dem_f[rowA] / (EpA * s1a + EmA * s2a);
    float scB = dem_f[rowA + 1] / (EpB * s1b + EmB * s2b);
    float ePA = EpA * scA, eMA = EmA * scA;
    float ePB = EpB * scB, eMB = EmB * scB;

    // Write: FULL rows this time — 16 segs x 64 lanes = 1024 float4 per row.
    // Wave covers 32KB contiguous (2 adjacent rows); block 128KB; grid = linear
    // sweep of the 134MB output, fill-like. Zero VMEM loads in the loop.
    f32x4* outA = (f32x4*)(out_g + (size_t)rowA * N);
    #pragma unroll
    for (int q = 0; q < 16; ++q) {
        int idx = q * 64 + lane;
        float4 fp = ((const float4*)sFp)[idx];
        float4 fm = ((const float4*)sFm)[idx];
        f32x4 o;
        o.x = fp.x > thrA ? ePA * fp.x : eMA * fm.x;
        o.y = fp.y > thrA ? ePA * fp.y : eMA * fm.y;
        o.z = fp.z > thrA ? ePA * fp.z : eMA * fm.z;
        o.w = fp.w > thrA ? ePA * fp.w : eMA * fm.w;
        outA[idx] = o;
        f32x4 o2;
        o2.x = fp.x > thrB ? ePB * fp.x : eMB * fm.x;
        o2.y = fp.y > thrB ? ePB * fp.y : eMB * fm.y;
        o2.z = fp.z > thrB ? ePB * fp.z : eMB * fm.z;
        o2.w = fp.w > thrB ? ePB * fp.w : eMB * fm.w;
        outA[1024 + idx] = o2;
    }
}

extern "C" void kernel_launch(void* const* d_in, const int* in_sizes, int n_in,
                              void* d_out, int out_size, void* d_ws, size_t ws_size,
                              hipStream_t stream) {
    // inputs: 0 embed_feat(f32 B*N*D), 1 predict_G(int,ignored), 2 W_demand(f32 D),
    //         3 b_demand(f32 1), 4 Wa(f32 D*D), 5 w_l(f32 D), 6 w_r(f32 D)
    const float* x  = (const float*)d_in[0];
    const float* Wd = (const float*)d_in[2];
    const float* bd = (const float*)d_in[3];
    const float* Wa = (const float*)d_in[4];
    const float* wl = (const float*)d_in[5];
    const float* wr = (const float*)d_in[6];

    float* ws = (float*)d_ws;
    float* lv   = ws;                 // 8192 floats
    float* colR = ws + 8192;          // 8192 floats

    float* out     = (float*)d_out;
    float* out_dem = out;             // [B*N]
    float* out_g   = out + B * N;     // [B,N,N] (byte off 32768, 16B-aligned)

    hipLaunchKernelGGL(kA_rows, dim3(B * N / 16), dim3(256), 0, stream,
                       x, Wd, bd, Wa, wl, wr, out_dem, lv, colR);
    hipLaunchKernelGGL(kB_write, dim3(B * N / 8), dim3(256), 0, stream,
                       lv, colR, out_dem, out_g);
}